// Round 1
// baseline (259.285 us; speedup 1.0000x reference)
//
#include <hip/hip_runtime.h>

#define TW 32
#define TH 32
#define EX 42            // 32 + 2*5 halo
#define SXS 43           // padded LDS stride for input tiles
#define HS  33           // padded LDS stride for horizontal results
#define IMG_W 512
#define IMG_H 512
#define NPLANES 48       // 16 * 3
#define NPIX 12582912.0  // 16*3*512*512

__global__ __launch_bounds__(256) void ssim_fused_kernel(
    const float* __restrict__ pred,
    const float* __restrict__ label,
    double* __restrict__ accum)
{
    __shared__ float sx[EX][SXS];
    __shared__ float sy[EX][SXS];
    __shared__ float hX [EX][HS];
    __shared__ float hY [EX][HS];
    __shared__ float hXX[EX][HS];
    __shared__ float hYY[EX][HS];
    __shared__ float hXY[EX][HS];

    const int tid = threadIdx.x;
    const int ox = blockIdx.x * TW;
    const int oy = blockIdx.y * TH;
    const int plane = blockIdx.z;
    const float* __restrict__ xp = pred  + (size_t)plane * IMG_W * IMG_H;
    const float* __restrict__ yp = label + (size_t)plane * IMG_W * IMG_H;

    // Gaussian weights (sigma=1.5, K=11), normalized — computed once per thread.
    float w[11];
    {
        float s = 0.f;
        #pragma unroll
        for (int i = 0; i < 11; ++i) {
            float d = (float)(i - 5);
            w[i] = expf(-d * d / 4.5f);
            s += w[i];
        }
        float inv = 1.0f / s;
        #pragma unroll
        for (int i = 0; i < 11; ++i) w[i] *= inv;
    }

    // ---- Stage extended tile (zero-padded at image borders) ----
    for (int i = tid; i < EX * EX; i += 256) {
        int r = i / EX;
        int c = i - r * EX;
        int gy = oy - 5 + r;
        int gx = ox - 5 + c;
        float xv = 0.f, yv = 0.f;
        if (gy >= 0 && gy < IMG_H && gx >= 0 && gx < IMG_W) {
            int idx = gy * IMG_W + gx;
            xv = xp[idx];
            yv = yp[idx];
        }
        sx[r][c] = xv;
        sy[r][c] = yv;
    }
    __syncthreads();

    // ---- Horizontal 11-tap pass for 5 fields: x, y, x^2, y^2, x*y ----
    for (int i = tid; i < EX * TW; i += 256) {
        int r = i >> 5;        // TW == 32
        int c = i & 31;
        float ax = 0.f, ay = 0.f, axx = 0.f, ayy = 0.f, axy = 0.f;
        #pragma unroll
        for (int k = 0; k < 11; ++k) {
            float wk = w[k];
            float xv = sx[r][c + k];
            float yv = sy[r][c + k];
            ax  += wk * xv;
            ay  += wk * yv;
            axx += wk * xv * xv;
            ayy += wk * yv * yv;
            axy += wk * xv * yv;
        }
        hX [r][c] = ax;
        hY [r][c] = ay;
        hXX[r][c] = axx;
        hYY[r][c] = ayy;
        hXY[r][c] = axy;
    }
    __syncthreads();

    // ---- Vertical 11-tap pass + SSIM map + local accumulation ----
    float lsum = 0.f;
    for (int i = tid; i < TH * TW; i += 256) {
        int r = i >> 5;
        int c = i & 31;
        float mu1 = 0.f, mu2 = 0.f, cxx = 0.f, cyy = 0.f, cxy = 0.f;
        #pragma unroll
        for (int k = 0; k < 11; ++k) {
            float wk = w[k];
            mu1 += wk * hX [r + k][c];
            mu2 += wk * hY [r + k][c];
            cxx += wk * hXX[r + k][c];
            cyy += wk * hYY[r + k][c];
            cxy += wk * hXY[r + k][c];
        }
        float mu1s = mu1 * mu1;
        float mu2s = mu2 * mu2;
        float mu12 = mu1 * mu2;
        float s1  = cxx - mu1s;
        float s2  = cyy - mu2s;
        float s12 = cxy - mu12;
        const float C1 = 1e-4f;   // 0.01^2
        const float C2 = 9e-4f;   // 0.03^2
        float num = (2.f * mu12 + C1) * (2.f * s12 + C2);
        float den = (mu1s + mu2s + C1) * (s1 + s2 + C2);
        lsum += num / den;
    }

    // ---- Block reduction: wave shuffle then cross-wave via LDS ----
    #pragma unroll
    for (int off = 32; off > 0; off >>= 1)
        lsum += __shfl_down(lsum, off, 64);

    __shared__ float wsum[4];
    if ((tid & 63) == 0) wsum[tid >> 6] = lsum;
    __syncthreads();
    if (tid == 0) {
        float b = wsum[0] + wsum[1] + wsum[2] + wsum[3];
        atomicAdd(accum, (double)b);
    }
}

__global__ void ssim_finalize_kernel(const double* __restrict__ accum,
                                     float* __restrict__ out)
{
    out[0] = 1.0f - (float)(accum[0] / NPIX);
}

extern "C" void kernel_launch(void* const* d_in, const int* in_sizes, int n_in,
                              void* d_out, int out_size, void* d_ws, size_t ws_size,
                              hipStream_t stream) {
    const float* pred  = (const float*)d_in[0];
    const float* label = (const float*)d_in[1];
    float* out = (float*)d_out;
    double* acc = (double*)d_ws;

    // d_ws is poisoned (0xAA) before every launch — zero the accumulator.
    hipMemsetAsync(d_ws, 0, sizeof(double), stream);

    dim3 grid(IMG_W / TW, IMG_H / TH, NPLANES);
    ssim_fused_kernel<<<grid, 256, 0, stream>>>(pred, label, acc);
    ssim_finalize_kernel<<<1, 1, 0, stream>>>(acc, out);
}

// Round 3
// 192.839 us; speedup vs baseline: 1.3446x; 1.3446x over previous
//
#include <hip/hip_runtime.h>

#define IMG_W 512
#define IMG_H 512
#define NPLANES 48        // 16 * 3
#define NPIX 12582912.0   // 16*3*512*512
#define HT_STRIDE 44      // 42 ext rows padded to 44 (16B-aligned, 2-way bank alias = free)
#define NBLOCKS (16*16*48)

__global__ __launch_bounds__(256) void ssim_fused_kernel(
    const float* __restrict__ pred,
    const float* __restrict__ label,
    float* __restrict__ partial)
{
    // h-fields stored TRANSPOSED: hT[field][tile_col][ext_row]
    __shared__ float hT[5][32][HT_STRIDE];

    const int tid = threadIdx.x;
    const int ox = blockIdx.x * 32;
    const int oy = blockIdx.y * 32;
    const int plane = blockIdx.z;
    const float* __restrict__ xp = pred  + (size_t)plane * IMG_W * IMG_H;
    const float* __restrict__ yp = label + (size_t)plane * IMG_W * IMG_H;

    // Gaussian weights (sigma=1.5, K=11), normalized.
    float w[11];
    {
        float s = 0.f;
        #pragma unroll
        for (int i = 0; i < 11; ++i) {
            float d = (float)(i - 5);
            w[i] = expf(-d * d / 4.5f);
            s += w[i];
        }
        float inv = 1.0f / s;
        #pragma unroll
        for (int i = 0; i < 11; ++i) w[i] *= inv;
    }

    // ---- Horizontal pass: 42 ext rows x 8 groups of 4 cols = 336 tasks ----
    // Each task: load 24-float window (6 aligned float4) per input, compute
    // products once per column, accumulate 4 outputs x 5 fields.
    const bool xInterior = (blockIdx.x != 0) && (blockIdx.x != (IMG_W / 32 - 1));
    for (int i = tid; i < 336; i += 256) {
        int r  = i >> 3;          // ext row 0..41
        int g  = i & 7;           // col group 0..7
        int gy = oy - 5 + r;
        int c0 = ox + g * 4;      // first output col of this group (global)

        float bx_[24], by_[24];
        bool rowok = ((unsigned)gy < (unsigned)IMG_H);
        if (!rowok) {
            #pragma unroll
            for (int j = 0; j < 24; ++j) { bx_[j] = 0.f; by_[j] = 0.f; }
        } else if (xInterior) {
            const float4* px4 = reinterpret_cast<const float4*>(xp + gy * IMG_W + (c0 - 8));
            const float4* py4 = reinterpret_cast<const float4*>(yp + gy * IMG_W + (c0 - 8));
            #pragma unroll
            for (int j = 0; j < 6; ++j) {
                float4 a = px4[j];
                float4 b = py4[j];
                bx_[4*j+0] = a.x; bx_[4*j+1] = a.y; bx_[4*j+2] = a.z; bx_[4*j+3] = a.w;
                by_[4*j+0] = b.x; by_[4*j+1] = b.y; by_[4*j+2] = b.z; by_[4*j+3] = b.w;
            }
        } else {
            #pragma unroll
            for (int j = 0; j < 24; ++j) {
                int col = c0 - 8 + j;
                bool ok = ((unsigned)col < (unsigned)IMG_W);
                bx_[j] = ok ? xp[gy * IMG_W + col] : 0.f;
                by_[j] = ok ? yp[gy * IMG_W + col] : 0.f;
            }
        }

        float a0[4] = {0,0,0,0}, a1[4] = {0,0,0,0}, a2[4] = {0,0,0,0},
              a3[4] = {0,0,0,0}, a4[4] = {0,0,0,0};
        // window element j covers global col c0-8+j; output o needs taps at
        // cols c0+o-5 .. c0+o+5  ->  j = o+3 .. o+13
        #pragma unroll
        for (int j = 3; j <= 16; ++j) {
            float xv = bx_[j], yv = by_[j];
            float xx = xv * xv, yy = yv * yv, xy = xv * yv;
            #pragma unroll
            for (int o = 0; o < 4; ++o) {
                int k = j - 3 - o;
                if (k >= 0 && k <= 10) {
                    float wk = w[k];
                    a0[o] += wk * xv;
                    a1[o] += wk * yv;
                    a2[o] += wk * xx;
                    a3[o] += wk * yy;
                    a4[o] += wk * xy;
                }
            }
        }
        #pragma unroll
        for (int o = 0; o < 4; ++o) {
            int c = g * 4 + o;    // tile-local col
            hT[0][c][r] = a0[o];
            hT[1][c][r] = a1[o];
            hT[2][c][r] = a2[o];
            hT[3][c][r] = a3[o];
            hT[4][c][r] = a4[o];
        }
    }
    __syncthreads();

    // ---- Vertical pass: 32 cols x 8 groups of 4 rows = 256 tasks ----
    // Reads per field: 14 needed values as 4 x ds_read_b128 (16 floats).
    {
        int c  = tid & 31;
        int rg = tid >> 5;
        int rb = rg * 4;          // first tile-local output row; ext rows rb..rb+13

        float m[5][4];
        #pragma unroll
        for (int f = 0; f < 5; ++f) {
            const float4* p = reinterpret_cast<const float4*>(&hT[f][c][rb]);
            float4 v0 = p[0], v1 = p[1], v2 = p[2], v3 = p[3];
            float vv[16] = { v0.x, v0.y, v0.z, v0.w,
                             v1.x, v1.y, v1.z, v1.w,
                             v2.x, v2.y, v2.z, v2.w,
                             v3.x, v3.y, v3.z, v3.w };
            #pragma unroll
            for (int o = 0; o < 4; ++o) {
                float s = 0.f;
                #pragma unroll
                for (int k = 0; k < 11; ++k) s += w[k] * vv[o + k];
                m[f][o] = s;
            }
        }

        float lsum = 0.f;
        #pragma unroll
        for (int o = 0; o < 4; ++o) {
            float mu1 = m[0][o], mu2 = m[1][o];
            float mu1s = mu1 * mu1, mu2s = mu2 * mu2, mu12 = mu1 * mu2;
            float s1  = m[2][o] - mu1s;
            float s2  = m[3][o] - mu2s;
            float s12 = m[4][o] - mu12;
            const float C1 = 1e-4f, C2 = 9e-4f;
            float num = (2.f * mu12 + C1) * (2.f * s12 + C2);
            float den = (mu1s + mu2s + C1) * (s1 + s2 + C2);
            lsum += num / den;
        }

        // ---- Block reduction -> one float partial per block ----
        #pragma unroll
        for (int off = 32; off > 0; off >>= 1)
            lsum += __shfl_down(lsum, off, 64);

        __shared__ float wsum[4];
        if ((tid & 63) == 0) wsum[tid >> 6] = lsum;
        __syncthreads();
        if (tid == 0) {
            int bid = (blockIdx.z * gridDim.y + blockIdx.y) * gridDim.x + blockIdx.x;
            partial[bid] = wsum[0] + wsum[1] + wsum[2] + wsum[3];
        }
    }
}

__global__ __launch_bounds__(256) void ssim_finalize_kernel(
    const float* __restrict__ partial, float* __restrict__ out)
{
    double s = 0.0;
    for (int i = threadIdx.x; i < NBLOCKS; i += 256) s += (double)partial[i];
    #pragma unroll
    for (int off = 32; off > 0; off >>= 1) s += __shfl_down(s, off, 64);
    __shared__ double ws[4];
    if ((threadIdx.x & 63) == 0) ws[threadIdx.x >> 6] = s;
    __syncthreads();
    if (threadIdx.x == 0)
        out[0] = 1.0f - (float)((ws[0] + ws[1] + ws[2] + ws[3]) / NPIX);
}

extern "C" void kernel_launch(void* const* d_in, const int* in_sizes, int n_in,
                              void* d_out, int out_size, void* d_ws, size_t ws_size,
                              hipStream_t stream) {
    const float* pred  = (const float*)d_in[0];
    const float* label = (const float*)d_in[1];
    float* out = (float*)d_out;
    float* partial = (float*)d_ws;   // NBLOCKS floats, fully overwritten every call

    dim3 grid(IMG_W / 32, IMG_H / 32, NPLANES);
    ssim_fused_kernel<<<grid, 256, 0, stream>>>(pred, label, partial);
    ssim_finalize_kernel<<<1, 256, 0, stream>>>(partial, out);
}